// Round 3
// baseline (197.842 us; speedup 1.0000x reference)
//
#include <hip/hip_runtime.h>
#include <stdint.h>

#define H 8
#define DH 96
#define L 2048
#define NB 2
#define D 768

typedef unsigned short u16;
typedef unsigned int u32;
typedef __attribute__((ext_vector_type(8))) __bf16 bf16x8;
typedef __attribute__((ext_vector_type(4))) float f32x4;
typedef __attribute__((ext_vector_type(4))) u32 u32x4;

static __device__ __forceinline__ u16 f2bf(float f) {
  union { float f; u32 i; } v; v.f = f;
  u32 u = v.i;
  return (u16)((u + 0x7FFFu + ((u >> 16) & 1u)) >> 16);
}

// load 8 contiguous f32 and round-to-nearest-even to bf16x8
static __device__ __forceinline__ bf16x8 cvt8(const float* p) {
  f32x4 a = *(const f32x4*)p;
  f32x4 b = *(const f32x4*)(p + 4);
  bf16x8 r;
  r[0] = (__bf16)a[0]; r[1] = (__bf16)a[1]; r[2] = (__bf16)a[2]; r[3] = (__bf16)a[3];
  r[4] = (__bf16)b[0]; r[5] = (__bf16)b[1]; r[6] = (__bf16)b[2]; r[7] = (__bf16)b[3];
  return r;
}

// ---------------------------------------------------------------------------
// Fused QKV projection + RoPE (z=0: Q, z=1: K, z=2: V->V^T)
// A, W are float32; converted to bf16 at LDS staging. GEMM-BT:
// out[row,col] = sum_k A[row,k]*W[col,k]; M=4096, N=768, K=768.
// 128x128 tile, 4 waves (2x2 of 64x64), BK=32, 16x16x32 bf16 MFMA.
// ---------------------------------------------------------------------------
__global__ __launch_bounds__(256, 2)
void proj_qkv(const float* __restrict__ Qin, const float* __restrict__ Kin,
              const float* __restrict__ Vin,
              const float* __restrict__ Wq, const float* __restrict__ Wk,
              const float* __restrict__ Wv,
              const float* __restrict__ cq, const float* __restrict__ ck,
              u16* __restrict__ qo, u16* __restrict__ ko, u16* __restrict__ vo)
{
  __shared__ u16 a_lds[128 * 40];   // [128][32] padded to 40
  __shared__ u16 b_lds[128 * 40];
  const int tid = threadIdx.x;
  const int lane = tid & 63;
  const int w = tid >> 6;
  const int wr = w >> 1, wc = w & 1;
  const int z = blockIdx.z;
  const int row0 = blockIdx.y * 128;
  const int col0 = blockIdx.x * 128;

  const float* A = (z == 0) ? Qin : ((z == 1) ? Kin : Vin);
  const float* W = (z == 0) ? Wq : ((z == 1) ? Wk : Wv);

  f32x4 acc[4][4] = {};

  const int srow = tid >> 2;         // 0..63
  const int scol = (tid & 3) * 8;    // 0,8,16,24 elements
  const float* Ab = A + (size_t)row0 * D;
  const float* Wb = W + (size_t)col0 * D;
  const int fr = lane & 15;
  const int fk = (lane >> 4) * 8;

  for (int k0 = 0; k0 < D; k0 += 32) {
    __syncthreads();
    bf16x8 va0 = cvt8(Ab + (size_t)srow * D + k0 + scol);
    bf16x8 va1 = cvt8(Ab + (size_t)(srow + 64) * D + k0 + scol);
    bf16x8 vb0 = cvt8(Wb + (size_t)srow * D + k0 + scol);
    bf16x8 vb1 = cvt8(Wb + (size_t)(srow + 64) * D + k0 + scol);
    *(bf16x8*)(a_lds + srow * 40 + scol) = va0;
    *(bf16x8*)(a_lds + (srow + 64) * 40 + scol) = va1;
    *(bf16x8*)(b_lds + srow * 40 + scol) = vb0;
    *(bf16x8*)(b_lds + (srow + 64) * 40 + scol) = vb1;
    __syncthreads();
    bf16x8 af[4], bfr[4];
#pragma unroll
    for (int m = 0; m < 4; m++)
      af[m] = *(const bf16x8*)(a_lds + (wr * 64 + m * 16 + fr) * 40 + fk);
#pragma unroll
    for (int n = 0; n < 4; n++)
      bfr[n] = *(const bf16x8*)(b_lds + (wc * 64 + n * 16 + fr) * 40 + fk);
#pragma unroll
    for (int m = 0; m < 4; m++)
#pragma unroll
      for (int n = 0; n < 4; n++)
        acc[m][n] = __builtin_amdgcn_mfma_f32_16x16x32_bf16(af[m], bfr[n], acc[m][n], 0, 0, 0);
  }

  if (z == 2) {
    // store V transposed: vt[((b*H + h)*96 + dd) * L + l]
#pragma unroll
    for (int m = 0; m < 4; m++) {
      int rbase = row0 + wr * 64 + m * 16 + (lane >> 4) * 4;
#pragma unroll
      for (int n = 0; n < 4; n++) {
        int c = col0 + wc * 64 + n * 16 + fr;
        int hh = c / DH, dd = c % DH;
#pragma unroll
        for (int r = 0; r < 4; r++) {
          int row = rbase + r;
          int b = row >> 11, l = row & (L - 1);
          vo[((size_t)((b * H + hh) * DH + dd)) * L + l] = f2bf(acc[m][n][r]);
        }
      }
    }
  } else {
    // RoPE-3D epilogue. Column blocks of 32 never cross a head boundary
    // (96 = 3*32); rotate-half partner (dd, dd+16) = fragments (n, n+1)
    // at the same lane. Store q/k as [B,H,L,96].
    const float* coords = (z == 0) ? cq : ck;
    u16* outp = (z == 0) ? qo : ko;
#pragma unroll
    for (int m = 0; m < 4; m++) {
      int rbase = row0 + wr * 64 + m * 16 + (lane >> 4) * 4;
#pragma unroll
      for (int np = 0; np < 2; np++) {
        int n1 = np * 2;
        int c1 = col0 + wc * 64 + n1 * 16 + fr;
        int hh = c1 / DH;
        int dd1 = c1 % DH;
        int axis = dd1 / 32;
        int j = dd1 & 15;
        // inv_freq = 10000^(-j/16) = 2^(-j*log2(10000)/16)
        float invf = exp2f(-(float)j * 0.83048202372184058f);
#pragma unroll
        for (int r = 0; r < 4; r++) {
          int row = rbase + r;
          int b = row >> 11, l = row & (L - 1);
          float coord = coords[((size_t)(b * L + l)) * 3 + axis];
          float ang = coord * invf;
          float sn = __sinf(ang), cs = __cosf(ang);
          float x1 = acc[m][n1][r], x2 = acc[m][n1 + 1][r];
          size_t base = ((size_t)((b * H + hh) * L + l)) * DH;
          outp[base + dd1] = f2bf(x1 * cs - x2 * sn);
          outp[base + dd1 + 16] = f2bf(x1 * sn + x2 * cs);
        }
      }
    }
  }
}

// ---------------------------------------------------------------------------
// Flash attention: one block = 64 q-rows of one (b,h); 4 waves x 16 rows.
// K/V tiles of 64 staged in LDS; online softmax; P via padded LDS.
// Workspace tensors are bf16.
// ---------------------------------------------------------------------------
__global__ __launch_bounds__(256, 2)
void attn_fwd(const u16* __restrict__ q_ws, const u16* __restrict__ k_ws,
              const u16* __restrict__ vt_ws, u16* __restrict__ ao)
{
  __shared__ u16 k_lds[64 * 96];        // rows stride 192B
  __shared__ u16 vt_lds[96 * 72];       // [96][64] padded to 72
  __shared__ u16 p_lds[4][16 * 80];     // per-wave [16][64] padded to 80
  const int tid = threadIdx.x;
  const int lane = tid & 63;
  const int w = tid >> 6;
  const int bh = blockIdx.y;
  const int q0 = blockIdx.x * 64;
  const float scale = 0.10206207261596575f;  // 96^-0.5

  const int fr = lane & 15;
  const int fko = (lane >> 4) * 8;

  // Q fragments held in registers for the whole block (A-frag layout)
  bf16x8 qf[3];
  const u16* qbase = q_ws + ((size_t)bh * L + q0 + w * 16 + fr) * DH;
#pragma unroll
  for (int ks = 0; ks < 3; ks++)
    qf[ks] = *(const bf16x8*)(qbase + ks * 32 + fko);

  f32x4 o[6] = {};
  float m_r[4], l_r[4];
#pragma unroll
  for (int r = 0; r < 4; r++) { m_r[r] = -1e30f; l_r[r] = 0.f; }

  const u16* kbase = k_ws + (size_t)bh * L * DH;
  const u16* vtbase = vt_ws + (size_t)bh * DH * L;

  for (int kt = 0; kt < L; kt += 64) {
    __syncthreads();
    // stage K tile [64][96]: 768 16B-chunks over 256 threads
    {
      int ch = tid;
#pragma unroll
      for (int it = 0; it < 3; it++, ch += 256) {
        int row = ch / 12, off = (ch % 12) * 8;
        *(u32x4*)(k_lds + row * 96 + off) =
            *(const u32x4*)(kbase + (size_t)(kt + row) * DH + off);
      }
      int ch2 = tid;  // V^T tile [96][64]: 768 chunks
#pragma unroll
      for (int it = 0; it < 3; it++, ch2 += 256) {
        int row = ch2 >> 3, off = (ch2 & 7) * 8;
        *(u32x4*)(vt_lds + row * 72 + off) =
            *(const u32x4*)(vtbase + (size_t)row * L + kt + off);
      }
    }
    __syncthreads();

    // S = Q K^T : 4 n-frags x 3 k-steps
    f32x4 s[4] = {};
#pragma unroll
    for (int n = 0; n < 4; n++)
#pragma unroll
      for (int ks = 0; ks < 3; ks++) {
        bf16x8 kf = *(const bf16x8*)(k_lds + (n * 16 + fr) * 96 + ks * 32 + fko);
        s[n] = __builtin_amdgcn_mfma_f32_16x16x32_bf16(qf[ks], kf, s[n], 0, 0, 0);
      }

    // online softmax (rows live on regs r, spread over 16 lanes)
    float mnew[4], alpha[4];
#pragma unroll
    for (int r = 0; r < 4; r++) {
      float mx = fmaxf(fmaxf(s[0][r], s[1][r]), fmaxf(s[2][r], s[3][r]));
#pragma unroll
      for (int d = 1; d < 16; d <<= 1)
        mx = fmaxf(mx, __shfl_xor(mx, d));
      mx *= scale;
      float mn = fmaxf(m_r[r], mx);
      alpha[r] = __expf(m_r[r] - mn);
      m_r[r] = mn;
      mnew[r] = mn;
    }
#pragma unroll
    for (int r = 0; r < 4; r++) {
      float rs = 0.f;
#pragma unroll
      for (int n = 0; n < 4; n++) {
        float p = __expf(s[n][r] * scale - mnew[r]);
        rs += p;
        p_lds[w][((lane >> 4) * 4 + r) * 80 + n * 16 + fr] = f2bf(p);
      }
#pragma unroll
      for (int d = 1; d < 16; d <<= 1)
        rs += __shfl_xor(rs, d);
      l_r[r] = l_r[r] * alpha[r] + rs;
    }
#pragma unroll
    for (int nf = 0; nf < 6; nf++)
#pragma unroll
      for (int r = 0; r < 4; r++)
        o[nf][r] *= alpha[r];

    // PV: A = P (own wave's LDS rows), B = V^T tile
#pragma unroll
    for (int ks = 0; ks < 2; ks++) {
      bf16x8 pf = *(const bf16x8*)(&p_lds[w][fr * 80 + ks * 32 + fko]);
#pragma unroll
      for (int nf = 0; nf < 6; nf++) {
        bf16x8 vf = *(const bf16x8*)(vt_lds + (nf * 16 + fr) * 72 + ks * 32 + fko);
        o[nf] = __builtin_amdgcn_mfma_f32_16x16x32_bf16(pf, vf, o[nf], 0, 0, 0);
      }
    }
  }

  // epilogue: ao[b, l, h*96 + dd], bf16
  const int b = bh >> 3, hh = bh & 7;
#pragma unroll
  for (int r = 0; r < 4; r++) {
    int l = q0 + w * 16 + (lane >> 4) * 4 + r;
    float inv = 1.f / l_r[r];
    size_t base = ((size_t)(b * L + l)) * D + hh * DH;
#pragma unroll
    for (int nf = 0; nf < 6; nf++)
      ao[base + nf * 16 + fr] = f2bf(o[nf][r] * inv);
  }
}

// ---------------------------------------------------------------------------
// Output projection: out = AO @ Wo^T; AO is bf16 ws, Wo is f32, out FLOAT32.
// ---------------------------------------------------------------------------
__global__ __launch_bounds__(256, 2)
void gemm_out(const u16* __restrict__ A, const float* __restrict__ W,
              float* __restrict__ out)
{
  __shared__ u16 a_lds[128 * 40];
  __shared__ u16 b_lds[128 * 40];
  const int tid = threadIdx.x;
  const int lane = tid & 63;
  const int w = tid >> 6;
  const int wr = w >> 1, wc = w & 1;
  const int row0 = blockIdx.y * 128;
  const int col0 = blockIdx.x * 128;

  f32x4 acc[4][4] = {};
  const int srow = tid >> 2;
  const int scol = (tid & 3) * 8;
  const u16* Ab = A + (size_t)row0 * D;
  const float* Wb = W + (size_t)col0 * D;
  const int fr = lane & 15;
  const int fk = (lane >> 4) * 8;

  for (int k0 = 0; k0 < D; k0 += 32) {
    __syncthreads();
    bf16x8 va0 = *(const bf16x8*)(Ab + (size_t)srow * D + k0 + scol);
    bf16x8 va1 = *(const bf16x8*)(Ab + (size_t)(srow + 64) * D + k0 + scol);
    bf16x8 vb0 = cvt8(Wb + (size_t)srow * D + k0 + scol);
    bf16x8 vb1 = cvt8(Wb + (size_t)(srow + 64) * D + k0 + scol);
    *(bf16x8*)(a_lds + srow * 40 + scol) = va0;
    *(bf16x8*)(a_lds + (srow + 64) * 40 + scol) = va1;
    *(bf16x8*)(b_lds + srow * 40 + scol) = vb0;
    *(bf16x8*)(b_lds + (srow + 64) * 40 + scol) = vb1;
    __syncthreads();
    bf16x8 af[4], bfr[4];
#pragma unroll
    for (int m = 0; m < 4; m++)
      af[m] = *(const bf16x8*)(a_lds + (wr * 64 + m * 16 + fr) * 40 + fk);
#pragma unroll
    for (int n = 0; n < 4; n++)
      bfr[n] = *(const bf16x8*)(b_lds + (wc * 64 + n * 16 + fr) * 40 + fk);
#pragma unroll
    for (int m = 0; m < 4; m++)
#pragma unroll
      for (int n = 0; n < 4; n++)
        acc[m][n] = __builtin_amdgcn_mfma_f32_16x16x32_bf16(af[m], bfr[n], acc[m][n], 0, 0, 0);
  }

#pragma unroll
  for (int m = 0; m < 4; m++) {
    int rbase = row0 + wr * 64 + m * 16 + (lane >> 4) * 4;
#pragma unroll
    for (int n = 0; n < 4; n++) {
      int c = col0 + wc * 64 + n * 16 + fr;
#pragma unroll
      for (int r = 0; r < 4; r++)
        out[(size_t)(rbase + r) * D + c] = acc[m][n][r];
    }
  }
}

extern "C" void kernel_launch(void* const* d_in, const int* in_sizes, int n_in,
                              void* d_out, int out_size, void* d_ws, size_t ws_size,
                              hipStream_t stream) {
  (void)in_sizes; (void)n_in; (void)out_size;
  const float* Qin = (const float*)d_in[0];
  const float* Kin = (const float*)d_in[1];
  const float* Vin = (const float*)d_in[2];
  const float* cq  = (const float*)d_in[3];
  const float* ck  = (const float*)d_in[4];
  const float* Wq  = (const float*)d_in[5];
  const float* Wk  = (const float*)d_in[6];
  const float* Wv  = (const float*)d_in[7];
  const float* Wo  = (const float*)d_in[8];
  float* out = (float*)d_out;

  const size_t per = (size_t)NB * H * L * DH;  // 3,145,728 elems
  if (ws_size < 4 * per * sizeof(u16)) return;  // diagnostic: leaves out zeroed

  u16* q_ws  = (u16*)d_ws;
  u16* k_ws  = q_ws + per;
  u16* vt_ws = k_ws + per;
  u16* ao_ws = vt_ws + per;

  dim3 blk(256);
  proj_qkv<<<dim3(D / 128, (NB * L) / 128, 3), blk, 0, stream>>>(
      Qin, Kin, Vin, Wq, Wk, Wv, cq, ck, q_ws, k_ws, vt_ws);
  attn_fwd<<<dim3(L / 64, NB * H), blk, 0, stream>>>(q_ws, k_ws, vt_ws, ao_ws);
  gemm_out<<<dim3(D / 128, (NB * L) / 128), blk, 0, stream>>>(ao_ws, Wo, out);
}